// Round 19
// baseline (203.462 us; speedup 1.0000x reference)
//
#include <hip/hip_runtime.h>
#include <math.h>

// Problem constants (fixed by setup_inputs)
#define TOTAL  32768   // B * N_PER_MOL
#define NMOL   1024
#define NA     32
#define DIM    128
#define NRBF   50
#define NLAYER 6

typedef __attribute__((ext_vector_type(16))) float f32x16;
typedef _Float16 h2 __attribute__((ext_vector_type(2)));
typedef __fp16 hf8 __attribute__((ext_vector_type(8)));   // MFMA operand container

// ------------------------------------------------------------ LDS layout (bytes)
// Rows: 272 B (136 f16) -> 4-bank rotate per row.
// XBAG [0,17408): XB (phase A->P1) then AGG/t1 (C->P7), disjoint live ranges.
// XF   [17408,34816): xf (P1->P3) then VX (P7->next A); POS aliases in setup.
// CM64 [34816,50688): u64 [2][992] = {(gboff<<16)|foff, pk_f16(a0,a1)}
// head: molS @ [0,1056), hsum @ [2048,3072)
#define OFF_XBAG 0
#define OFF_XF   17408
#define OFF_POS  17408     // setup-only alias
#define OFF_CM   34816
#define LDS_TOTAL 50688    // 3 blocks/CU (3x50688 <= 163840)

// ------------------------------------------------------------ ws layout (bytes)
// Weights repacked for coalesced direct-from-global MFMA B-fragments:
//   wX[l][(k>>3)][col][k&7] f16, 128x128 per layer = 32768 B
#define WS_WIT   0          // 6 * 32768 = 196608
#define WS_WO1T  196608
#define WS_WO2T  393216
#define WS_TAB   655360     // 6 * 176*136*2 = 287232 (L2-resident, read direct)

#define KSTEP  0.10204081632653061f   /* 5/49 */
#define C1     -48.0200005f           /* -0.5*(49/5)^2 */
#define NTAB   176
#define TSCALE 35.0f                  /* 175/5 */

// ------------------------------------------------------------ helpers
__device__ __forceinline__ unsigned pk2_f16(float lo, float hi) {  // v_cvt_pkrtz_f16_f32
  return __builtin_bit_cast(unsigned, __builtin_amdgcn_cvt_pkrtz(lo, hi));
}
__device__ __forceinline__ float ssp_f(float v) {    // softplus(v) - ln2
  float e = __expf(-fabsf(v));
  return fmaxf(v, 0.0f) + __logf(1.0f + e) - 0.69314718055994531f;
}
__device__ __forceinline__ hf8 ldsH(const char* p) {      // one ds_read_b128
  return __builtin_bit_cast(hf8, *reinterpret_cast<const uint4*>(p));
}
__device__ __forceinline__ hf8 asH(uint4 u) {
  return __builtin_bit_cast(hf8, u);
}
// round-robin inverse map: (round r, atom i) -> partner j
__device__ __forceinline__ int inv_partner(int r, int i) {
  if (i == 31) return r;
  int mm = i - r; if (mm < 0) mm += 31;
  if (mm == 0) return 31;
  int jj = 2 * r - i; jj %= 31; if (jj < 0) jj += 31;
  return jj;
}

// ------------------------------------------------------------ weight prep (cold, f16)
__global__ void k_prep(const float* __restrict__ Wi, const float* __restrict__ Wo1,
                       const float* __restrict__ Wo2, short* __restrict__ ws) {
  const int kind = blockIdx.y, l = blockIdx.z;
  const int idx = blockIdx.x * 256 + threadIdx.x;   // 64*256 = 16384 = 128*128
  int k = idx >> 7, c = idx & 127;
  const float* s = (kind == 0) ? Wi : (kind == 1) ? Wo1 : Wo2;
  size_t base = (kind == 0) ? WS_WIT : (kind == 1) ? WS_WO1T : WS_WO2T;
  float v = s[(size_t)l * DIM * DIM + k * DIM + c];
  ws[base / 2 + (size_t)l * 16384 + (k >> 3) * 1024 + c * 8 + (k & 7)] =
      (short)__builtin_bit_cast(unsigned short, (_Float16)v);
}

// ------------------------------------------------------------ filter table (cold, f16)
__global__ void k_tab(const float* __restrict__ Wf1, const float* __restrict__ bf1,
                      const float* __restrict__ Wf2, const float* __restrict__ bf2,
                      short* __restrict__ tab) {
  __shared__ float fs[64];
  __shared__ float hs[128];
  const int g = blockIdx.x, l = blockIdx.y, c = threadIdx.x;
  const float d = (float)g * (5.0f / 175.0f);
  if (c < NRBF) { float tt = d - (float)c * KSTEP; fs[c] = __expf(C1 * tt * tt); }
  __syncthreads();
  float h = bf1[l * DIM + c];
#pragma unroll 5
  for (int k = 0; k < NRBF; ++k) h += fs[k] * Wf1[((size_t)l * NRBF + k) * DIM + c];
  hs[c] = ssp_f(h);
  __syncthreads();
  float wv = bf2[l * DIM + c];
#pragma unroll 8
  for (int k = 0; k < DIM; ++k) wv += hs[k] * Wf2[((size_t)l * DIM + k) * DIM + c];
  tab[((size_t)l * NTAB + g) * 136 + c] =
      (short)__builtin_bit_cast(unsigned short, (_Float16)wv);
}

// ------------------------------------------------------------ fully fused network
// 2 molecules per block; x resident in registers (16 f32/thread) through all
// 6 layers + pooling + head. Waves 0-3 -> mol A, 4-7 -> mol B. 3 blocks/CU.
// MFMA B-operands AND the interp table read straight from global
// (L1/L2-resident) -- the LDS pipe carries only xf/agg traffic.
__global__ __launch_bounds__(512, 6) void k_fused(
    const int* __restrict__ z, const float* __restrict__ pos,
    const float* __restrict__ emb,
    const short* __restrict__ wiT, const short* __restrict__ wo1T,
    const short* __restrict__ wo2T, const short* __restrict__ tabA,
    const float* __restrict__ bo1, const float* __restrict__ bo2,
    const float* __restrict__ Wh1, const float* __restrict__ bh1,
    const float* __restrict__ Wh2, const float* __restrict__ bh2,
    float* __restrict__ out) {
  extern __shared__ char sm[];
  const int t = threadIdx.x;
  const int bid = blockIdx.x;
  const int w = t >> 6, lane = t & 63, hl = lane >> 5, lr = lane & 31;
  const int m = w >> 2, wl = w & 3;        // m == t>>8
  const int ai = t & 31;                   // owned atom
  const int acg = (t >> 5) & 7;            // channel group
  const int cgo = acg * 16;                // byte offset (8 ch)

  char*  XBm = sm + OFF_XBAG + m * 8704;   // XB and AGG/t1 (disjoint live ranges)
  char*  AGm = XBm;
  char*  XFm = sm + OFF_XF + m * 8704;
  float* poss = (float*)(sm + OFF_POS);    // setup-only alias
  const char* CMm = sm + OFF_CM + m * 7936;

  // ================ setup (once) ================
  if (t < 192) poss[t] = pos[(size_t)bid * 192 + t];
  __syncthreads();
  // per-(round, atom) metadata: one u64 = {(gboff<<16)|foff, pk_f16(a0,a1)}
  for (int u = t; u < 2048; u += 512) {
    int m2 = u >> 10, e = u & 1023;
    if (e < 992) {
      int r = e >> 5, i = e & 31;
      int j = inv_partner(r, i);
      const float* pm = poss + m2 * 96;
      float dx = pm[j * 3 + 0] - pm[i * 3 + 0];
      float dy = pm[j * 3 + 1] - pm[i * 3 + 1];
      float dz = pm[j * 3 + 2] - pm[i * 3 + 2];
      float d = sqrtf(dx * dx + dy * dy + dz * dz);
      float rc = 0.5f * (__cosf(d * 0.62831853071795865f) + 1.0f);
      rc = (d < 5.0f) ? rc : 0.0f;
      float u0 = fminf(d * TSCALE, 174.0f);
      int g = (int)u0;
      float f = u0 - (float)g;
      uint2 me;
      me.x = ((unsigned)(g * 272) << 16) | (unsigned)(j * 272);
      me.y = pk2_f16((1.0f - f) * rc, f * rc);
      *(uint2*)(sm + OFF_CM + m2 * 7936 + e * 8) = me;
    }
  }
  // x init from embedding (registers)
  float xr[16];
  {
    const float* er = emb + (size_t)z[(bid * 2 + m) * NA + ai] * DIM;
    float4 e0 = *(const float4*)&er[acg * 8];
    float4 e1 = *(const float4*)&er[acg * 8 + 4];
    float4 e2 = *(const float4*)&er[64 + acg * 8];
    float4 e3 = *(const float4*)&er[64 + acg * 8 + 4];
    xr[0] = e0.x; xr[1] = e0.y; xr[2]  = e0.z; xr[3]  = e0.w;
    xr[4] = e1.x; xr[5] = e1.y; xr[6]  = e1.z; xr[7]  = e1.w;
    xr[8] = e2.x; xr[9] = e2.y; xr[10] = e2.z; xr[11] = e2.w;
    xr[12] = e3.x; xr[13] = e3.y; xr[14] = e3.z; xr[15] = e3.w;
  }
  __syncthreads();                           // metadata complete; POS dead

  // ================ 6 interaction layers ================
  for (int l = 0; l < NLAYER; ++l) {
    const short* wiL  = wiT  + (size_t)l * 16384;
    const short* wo1L = wo1T + (size_t)l * 16384;
    const short* wo2L = wo2T + (size_t)l * 16384;
    const char*  tabB = (const char*)(tabA + (size_t)l * NTAB * 136);
    const float bo1r = bo1[l * DIM + wl * 32 + lr];
    const float bo2r = bo2[l * DIM + wl * 32 + lr];
    const int col = wl * 32 + lr;

    // ---- A: xr += VX (l>0) ; XB <- xr ----
    if (l > 0) {
      uint4 v0 = *(const uint4*)(XFm + ai * 272 + cgo);
      uint4 v1 = *(const uint4*)(XFm + ai * 272 + cgo + 128);
      h2 hv;
      hv = __builtin_bit_cast(h2, v0.x); xr[0]  += (float)hv[0]; xr[1]  += (float)hv[1];
      hv = __builtin_bit_cast(h2, v0.y); xr[2]  += (float)hv[0]; xr[3]  += (float)hv[1];
      hv = __builtin_bit_cast(h2, v0.z); xr[4]  += (float)hv[0]; xr[5]  += (float)hv[1];
      hv = __builtin_bit_cast(h2, v0.w); xr[6]  += (float)hv[0]; xr[7]  += (float)hv[1];
      hv = __builtin_bit_cast(h2, v1.x); xr[8]  += (float)hv[0]; xr[9]  += (float)hv[1];
      hv = __builtin_bit_cast(h2, v1.y); xr[10] += (float)hv[0]; xr[11] += (float)hv[1];
      hv = __builtin_bit_cast(h2, v1.z); xr[12] += (float)hv[0]; xr[13] += (float)hv[1];
      hv = __builtin_bit_cast(h2, v1.w); xr[14] += (float)hv[0]; xr[15] += (float)hv[1];
    }
    {
      uint4 s0, s1;
      s0.x = pk2_f16(xr[0], xr[1]);   s0.y = pk2_f16(xr[2], xr[3]);
      s0.z = pk2_f16(xr[4], xr[5]);   s0.w = pk2_f16(xr[6], xr[7]);
      s1.x = pk2_f16(xr[8], xr[9]);   s1.y = pk2_f16(xr[10], xr[11]);
      s1.z = pk2_f16(xr[12], xr[13]); s1.w = pk2_f16(xr[14], xr[15]);
      *(uint4*)(XBm + ai * 272 + cgo) = s0;
      *(uint4*)(XBm + ai * 272 + cgo + 128) = s1;
    }
    __syncthreads();

    // ---- P1: xf = x @ Wi (A from LDS, B from global) ; epilogue -> f16 XF ----
    {
      uint4 bf[8];
#pragma unroll
      for (int ks = 0; ks < 8; ++ks)
        bf[ks] = *(const uint4*)(wiL + (ks * 2 + hl) * 1024 + col * 8);
      f32x16 acc;
#pragma unroll
      for (int q = 0; q < 16; ++q) acc[q] = 0.0f;
#pragma unroll
      for (int ks = 0; ks < 8; ++ks) {
        hf8 a = ldsH(XBm + lr * 272 + ks * 32 + hl * 16);
        acc = __builtin_amdgcn_mfma_f32_32x32x16_f16(a, asH(bf[ks]), acc, 0, 0, 0);
      }
#pragma unroll
      for (int rg = 0; rg < 16; rg += 2) {
        int row = (rg & 3) + 8 * (rg >> 2) + 4 * hl;
        unsigned pk = pk2_f16(acc[rg], acc[rg + 1]);
        *(unsigned short*)(XFm + row * 272 + col * 2) = (unsigned short)pk;
        *(unsigned short*)(XFm + (row + 1) * 272 + col * 2) = (unsigned short)(pk >> 16);
      }
    }
    __syncthreads();

    // ---- P3: aggregation, 31 rounds; T from global (VMEM), F+meta from LDS ----
    h2 acc_h[8];
#pragma unroll
    for (int q = 0; q < 8; ++q) acc_h[q] = (h2)(_Float16)0.0f;
#pragma unroll 2
    for (int r = 0; r < 31; ++r) {
      uint2 me = *(const uint2*)(CMm + ((r << 5) + ai) * 8);
      int foff = (int)(me.x & 0xFFFFu);
      int gboff = (int)(me.x >> 16);
      unsigned a = me.y;
      h2 a00h = __builtin_bit_cast(h2, __builtin_amdgcn_perm(a, a, 0x01000100u));
      h2 a11h = __builtin_bit_cast(h2, __builtin_amdgcn_perm(a, a, 0x03020302u));
      const char* tp = tabB + gboff + cgo;
      uint4 T00 = *(const uint4*)(tp);
      uint4 T01 = *(const uint4*)(tp + 128);
      uint4 T10 = *(const uint4*)(tp + 272);
      uint4 T11 = *(const uint4*)(tp + 400);
      const char* fp = XFm + foff + cgo;
      uint4 F0 = *(const uint4*)(fp);
      uint4 F1 = *(const uint4*)(fp + 128);
#define AGCH(q, t0u, t1u, fu)                                        \
      { h2 wv = a00h * __builtin_bit_cast(h2, t0u)                   \
              + a11h * __builtin_bit_cast(h2, t1u);                  \
        acc_h[q] = wv * __builtin_bit_cast(h2, fu) + acc_h[q]; }
      AGCH(0, T00.x, T10.x, F0.x)
      AGCH(1, T00.y, T10.y, F0.y)
      AGCH(2, T00.z, T10.z, F0.z)
      AGCH(3, T00.w, T10.w, F0.w)
      AGCH(4, T01.x, T11.x, F1.x)
      AGCH(5, T01.y, T11.y, F1.y)
      AGCH(6, T01.z, T11.z, F1.z)
      AGCH(7, T01.w, T11.w, F1.w)
#undef AGCH
    }
    __syncthreads();                     // XF reads done

    // ---- C: AGG <- acc_h (packed f16 direct store; overwrites dead XB) ----
    {
      uint4 s0, s1;
      s0.x = __builtin_bit_cast(unsigned, acc_h[0]);
      s0.y = __builtin_bit_cast(unsigned, acc_h[1]);
      s0.z = __builtin_bit_cast(unsigned, acc_h[2]);
      s0.w = __builtin_bit_cast(unsigned, acc_h[3]);
      s1.x = __builtin_bit_cast(unsigned, acc_h[4]);
      s1.y = __builtin_bit_cast(unsigned, acc_h[5]);
      s1.z = __builtin_bit_cast(unsigned, acc_h[6]);
      s1.w = __builtin_bit_cast(unsigned, acc_h[7]);
      *(uint4*)(AGm + ai * 272 + cgo) = s0;
      *(uint4*)(AGm + ai * 272 + cgo + 128) = s1;
    }
    __syncthreads();

    // ---- P5: t1 = ssp(agg @ Wo1 + bo1) (B from global) ----
    float t1v[16];
    {
      uint4 bf[8];
#pragma unroll
      for (int ks = 0; ks < 8; ++ks)
        bf[ks] = *(const uint4*)(wo1L + (ks * 2 + hl) * 1024 + col * 8);
      f32x16 acc;
#pragma unroll
      for (int q = 0; q < 16; ++q) acc[q] = 0.0f;
#pragma unroll
      for (int ks = 0; ks < 8; ++ks) {
        hf8 a = ldsH(AGm + lr * 272 + ks * 32 + hl * 16);
        acc = __builtin_amdgcn_mfma_f32_32x32x16_f16(a, asH(bf[ks]), acc, 0, 0, 0);
      }
#pragma unroll
      for (int rg = 0; rg < 16; ++rg) t1v[rg] = ssp_f(acc[rg] + bo1r);
    }
    __syncthreads();

    // ---- D: t1 -> AGm ----
    {
#pragma unroll
      for (int rg = 0; rg < 16; rg += 2) {
        int row = (rg & 3) + 8 * (rg >> 2) + 4 * hl;
        unsigned pk = pk2_f16(t1v[rg], t1v[rg + 1]);
        *(unsigned short*)(AGm + row * 272 + col * 2) = (unsigned short)pk;
        *(unsigned short*)(AGm + (row + 1) * 272 + col * 2) = (unsigned short)(pk >> 16);
      }
    }
    __syncthreads();

    // ---- P7: v = t1 @ Wo2 + bo2 -> VX f16 (XF region) ----
    {
      uint4 bf[8];
#pragma unroll
      for (int ks = 0; ks < 8; ++ks)
        bf[ks] = *(const uint4*)(wo2L + (ks * 2 + hl) * 1024 + col * 8);
      f32x16 acc;
#pragma unroll
      for (int q = 0; q < 16; ++q) acc[q] = 0.0f;
#pragma unroll
      for (int ks = 0; ks < 8; ++ks) {
        hf8 a = ldsH(AGm + lr * 272 + ks * 32 + hl * 16);
        acc = __builtin_amdgcn_mfma_f32_32x32x16_f16(a, asH(bf[ks]), acc, 0, 0, 0);
      }
#pragma unroll
      for (int rg = 0; rg < 16; rg += 2) {
        int row = (rg & 3) + 8 * (rg >> 2) + 4 * hl;
        unsigned pk = pk2_f16(acc[rg] + bo2r, acc[rg + 1] + bo2r);
        *(unsigned short*)(XFm + row * 272 + col * 2) = (unsigned short)pk;
        *(unsigned short*)(XFm + (row + 1) * 272 + col * 2) = (unsigned short)(pk >> 16);
      }
    }
    __syncthreads();
  }

  // ---- final residual: xr += VX (last layer) ----
  {
    uint4 v0 = *(const uint4*)(XFm + ai * 272 + cgo);
    uint4 v1 = *(const uint4*)(XFm + ai * 272 + cgo + 128);
    h2 hv;
    hv = __builtin_bit_cast(h2, v0.x); xr[0]  += (float)hv[0]; xr[1]  += (float)hv[1];
    hv = __builtin_bit_cast(h2, v0.y); xr[2]  += (float)hv[0]; xr[3]  += (float)hv[1];
    hv = __builtin_bit_cast(h2, v0.z); xr[4]  += (float)hv[0]; xr[5]  += (float)hv[1];
    hv = __builtin_bit_cast(h2, v0.w); xr[6]  += (float)hv[0]; xr[7]  += (float)hv[1];
    hv = __builtin_bit_cast(h2, v1.x); xr[8]  += (float)hv[0]; xr[9]  += (float)hv[1];
    hv = __builtin_bit_cast(h2, v1.y); xr[10] += (float)hv[0]; xr[11] += (float)hv[1];
    hv = __builtin_bit_cast(h2, v1.z); xr[12] += (float)hv[0]; xr[13] += (float)hv[1];
    hv = __builtin_bit_cast(h2, v1.w); xr[14] += (float)hv[0]; xr[15] += (float)hv[1];
  }

  // ================ pooling + head ================
#pragma unroll
  for (int off = 1; off < 32; off <<= 1) {
#pragma unroll
    for (int q = 0; q < 16; ++q) xr[q] += __shfl_xor(xr[q], off);
  }
  float* molS = (float*)(sm + 0);        // [2][132]
  float* hsum = (float*)(sm + 2048);     // [2][128]
  if (ai == 0) {
#pragma unroll
    for (int q = 0; q < 8; ++q) molS[m * 132 + acg * 8 + q] = xr[q];
#pragma unroll
    for (int q = 0; q < 8; ++q) molS[m * 132 + 64 + acg * 8 + q] = xr[8 + q];
  }
  __syncthreads();
  if (t < 256) {
    int mm = t >> 7, c = t & 127;
    float h = bh1[c];
#pragma unroll 8
    for (int k = 0; k < 128; ++k) h += molS[mm * 132 + k] * Wh1[k * 128 + c];
    h = h / (1.0f + __expf(-h));         // silu
    hsum[mm * 128 + c] = h * Wh2[c];
  }
  for (int off = 64; off > 0; off >>= 1) {
    __syncthreads();
    if (t < 256) {
      int mm = t >> 7, c = t & 127;
      if (c < off) hsum[mm * 128 + c] += hsum[mm * 128 + c + off];
    }
  }
  __syncthreads();
  if (t < 2) out[bid * 2 + t] = hsum[t * 128] + bh2[0];
}

// ------------------------------------------------------------ launcher
extern "C" void kernel_launch(void* const* d_in, const int* in_sizes, int n_in,
                              void* d_out, int out_size, void* d_ws, size_t ws_size,
                              hipStream_t stream) {
  const int*   z    = (const int*)d_in[0];
  const float* pos  = (const float*)d_in[1];
  const float* emb  = (const float*)d_in[6];
  const float* Wi   = (const float*)d_in[7];
  const float* Wf1  = (const float*)d_in[8];
  const float* bf1  = (const float*)d_in[9];
  const float* Wf2  = (const float*)d_in[10];
  const float* bf2  = (const float*)d_in[11];
  const float* Wo1  = (const float*)d_in[12];
  const float* bo1  = (const float*)d_in[13];
  const float* Wo2  = (const float*)d_in[14];
  const float* bo2  = (const float*)d_in[15];
  const float* Wh1  = (const float*)d_in[16];
  const float* bh1  = (const float*)d_in[17];
  const float* Wh2  = (const float*)d_in[18];
  const float* bh2  = (const float*)d_in[19];
  float* out = (float*)d_out;

  short* wsS = (short*)d_ws;
  const short* wiT  = wsS + WS_WIT  / 2;
  const short* wo1T = wsS + WS_WO1T / 2;
  const short* wo2T = wsS + WS_WO2T / 2;
  const short* tab  = wsS + WS_TAB  / 2;

  (void)hipFuncSetAttribute(reinterpret_cast<const void*>(k_fused),
                            hipFuncAttributeMaxDynamicSharedMemorySize, LDS_TOTAL);

  k_prep<<<dim3(64, 3, 6), 256, 0, stream>>>(Wi, Wo1, Wo2, wsS);
  k_tab<<<dim3(NTAB, 6), 128, 0, stream>>>(Wf1, bf1, Wf2, bf2, wsS + WS_TAB / 2);
  k_fused<<<NMOL / 2, 512, LDS_TOTAL, stream>>>(
      z, pos, emb, wiT, wo1T, wo2T, tab, bo1, bo2, Wh1, bh1, Wh2, bh2, out);
}

// Round 20
// 118.439 us; speedup vs baseline: 1.7179x; 1.7179x over previous
//
#include <hip/hip_runtime.h>
#include <math.h>

// Problem constants (fixed by setup_inputs)
#define TOTAL  32768   // B * N_PER_MOL
#define NMOL   1024
#define NA     32
#define DIM    128
#define NRBF   50
#define NLAYER 6

typedef __attribute__((ext_vector_type(16))) float f32x16;
typedef _Float16 h2 __attribute__((ext_vector_type(2)));
typedef __fp16 hf8 __attribute__((ext_vector_type(8)));   // MFMA operand container

// ------------------------------------------------------------ LDS layout (bytes)
// Rows: 272 B (136 f16) -> 4-bank rotate per row.
// TAB region [0, 46784) (NTAB=172); aliases:
//   XB (phase A->P1) and AGG/t1 (C->P7) share [29376,46784) -- disjoint lives.
// XF [46784,64192): xf (P1->P3) then VX (P7->next A); POS aliases in setup.
// CM [64192,81600): u64 meta TRANSPOSED [m][atom][round]: row = atom*272 B,
//   entry r at +r*8; rounds (2k,2k+1) read as one ds_read_b128. r=31 is a
//   zero pad (a=0 -> zero contribution).
#define OFF_TAB  0
#define OFF_XBAG 29376
#define OFF_XF   46784
#define OFF_POS  46784     // setup-only alias
#define OFF_CM   64192
#define LDS_TOTAL 81600    // 2 blocks/CU (2x81600 <= 163840)

// ------------------------------------------------------------ ws layout (bytes)
// Weights repacked for coalesced direct-from-global MFMA B-fragments:
//   wX[l][(k>>3)][col][k&7] f16, 128x128 per layer = 32768 B
#define WS_WIT   0          // 6 * 32768 = 196608
#define WS_WO1T  196608
#define WS_WO2T  393216
#define WS_TAB   655360     // 6 * 172*136*2 = 280704

#define KSTEP  0.10204081632653061f   /* 5/49 */
#define C1     -48.0200005f           /* -0.5*(49/5)^2 */
#define NTAB   172
#define TSCALE 34.2f                  /* 171/5 */

// ------------------------------------------------------------ helpers
__device__ __forceinline__ unsigned pk2_f16(float lo, float hi) {  // v_cvt_pkrtz_f16_f32
  return __builtin_bit_cast(unsigned, __builtin_amdgcn_cvt_pkrtz(lo, hi));
}
__device__ __forceinline__ float ssp_f(float v) {    // softplus(v) - ln2
  float e = __expf(-fabsf(v));
  return fmaxf(v, 0.0f) + __logf(1.0f + e) - 0.69314718055994531f;
}
__device__ __forceinline__ hf8 ldsH(const char* p) {      // one ds_read_b128
  return __builtin_bit_cast(hf8, *reinterpret_cast<const uint4*>(p));
}
__device__ __forceinline__ hf8 asH(uint4 u) {
  return __builtin_bit_cast(hf8, u);
}
// round-robin inverse map: (round r, atom i) -> partner j
__device__ __forceinline__ int inv_partner(int r, int i) {
  if (i == 31) return r;
  int mm = i - r; if (mm < 0) mm += 31;
  if (mm == 0) return 31;
  int jj = 2 * r - i; jj %= 31; if (jj < 0) jj += 31;
  return jj;
}

// ------------------------------------------------------------ weight prep (cold, f16)
__global__ void k_prep(const float* __restrict__ Wi, const float* __restrict__ Wo1,
                       const float* __restrict__ Wo2, short* __restrict__ ws) {
  const int kind = blockIdx.y, l = blockIdx.z;
  const int idx = blockIdx.x * 256 + threadIdx.x;   // 64*256 = 16384 = 128*128
  int k = idx >> 7, c = idx & 127;
  const float* s = (kind == 0) ? Wi : (kind == 1) ? Wo1 : Wo2;
  size_t base = (kind == 0) ? WS_WIT : (kind == 1) ? WS_WO1T : WS_WO2T;
  float v = s[(size_t)l * DIM * DIM + k * DIM + c];
  ws[base / 2 + (size_t)l * 16384 + (k >> 3) * 1024 + c * 8 + (k & 7)] =
      (short)__builtin_bit_cast(unsigned short, (_Float16)v);
}

// ------------------------------------------------------------ filter table (cold, f16)
__global__ void k_tab(const float* __restrict__ Wf1, const float* __restrict__ bf1,
                      const float* __restrict__ Wf2, const float* __restrict__ bf2,
                      short* __restrict__ tab) {
  __shared__ float fs[64];
  __shared__ float hs[128];
  const int g = blockIdx.x, l = blockIdx.y, c = threadIdx.x;
  const float d = (float)g * (5.0f / 171.0f);
  if (c < NRBF) { float tt = d - (float)c * KSTEP; fs[c] = __expf(C1 * tt * tt); }
  __syncthreads();
  float h = bf1[l * DIM + c];
#pragma unroll 5
  for (int k = 0; k < NRBF; ++k) h += fs[k] * Wf1[((size_t)l * NRBF + k) * DIM + c];
  hs[c] = ssp_f(h);
  __syncthreads();
  float wv = bf2[l * DIM + c];
#pragma unroll 8
  for (int k = 0; k < DIM; ++k) wv += hs[k] * Wf2[((size_t)l * DIM + k) * DIM + c];
  tab[((size_t)l * NTAB + g) * 136 + c] =
      (short)__builtin_bit_cast(unsigned short, (_Float16)wv);
}

// ------------------------------------------------------------ fully fused network
// 2 molecules per block; x resident in registers (16 f32/thread) through all
// 6 layers + pooling + head. Waves 0-3 -> mol A, 4-7 -> mol B. 2 blocks/CU.
// MFMA B-operands straight from global (coalesced, L1/L2-resident); interp
// table LDS-staged async (load-early / write-late).
__global__ __launch_bounds__(512, 4) void k_fused(
    const int* __restrict__ z, const float* __restrict__ pos,
    const float* __restrict__ emb,
    const short* __restrict__ wiT, const short* __restrict__ wo1T,
    const short* __restrict__ wo2T, const short* __restrict__ tabA,
    const float* __restrict__ bo1, const float* __restrict__ bo2,
    const float* __restrict__ Wh1, const float* __restrict__ bh1,
    const float* __restrict__ Wh2, const float* __restrict__ bh2,
    float* __restrict__ out) {
  extern __shared__ char sm[];
  const int t = threadIdx.x;
  const int bid = blockIdx.x;
  const int w = t >> 6, lane = t & 63, hl = lane >> 5, lr = lane & 31;
  const int m = w >> 2, wl = w & 3;        // m == t>>8
  const int ai = t & 31;                   // owned atom
  const int acg = (t >> 5) & 7;            // channel group
  const int cgo = acg * 16;                // byte offset (8 ch)

  char*  XBm = sm + OFF_XBAG + m * 8704;   // XB and AGG/t1 (disjoint live ranges)
  char*  AGm = XBm;
  char*  XFm = sm + OFF_XF + m * 8704;
  float* poss = (float*)(sm + OFF_POS);    // setup-only alias
  const char* CMm = sm + OFF_CM + m * 8704;

  // ================ setup (once) ================
  if (t < 192) poss[t] = pos[(size_t)bid * 192 + t];
  __syncthreads();
  // per-(atom, round) metadata, TRANSPOSED: entry (i, r) at i*272 + r*8.
  // u64 = {(gboff<<16)|foff, pk_f16(a0,a1)}; r=31 zero pad.
  for (int u = t; u < 2048; u += 512) {
    int m2 = u >> 10, e = u & 1023;
    int r = e >> 5, i = e & 31;
    uint2 me;
    if (r < 31) {
      int j = inv_partner(r, i);
      const float* pm = poss + m2 * 96;
      float dx = pm[j * 3 + 0] - pm[i * 3 + 0];
      float dy = pm[j * 3 + 1] - pm[i * 3 + 1];
      float dz = pm[j * 3 + 2] - pm[i * 3 + 2];
      float d = sqrtf(dx * dx + dy * dy + dz * dz);
      float rc = 0.5f * (__cosf(d * 0.62831853071795865f) + 1.0f);
      rc = (d < 5.0f) ? rc : 0.0f;
      float u0 = fminf(d * TSCALE, 170.0f);
      int g = (int)u0;
      float f = u0 - (float)g;
      me.x = ((unsigned)(g * 272) << 16) | (unsigned)(j * 272);
      me.y = pk2_f16((1.0f - f) * rc, f * rc);
    } else {
      me.x = 0u; me.y = 0u;               // a = 0 -> zero contribution
    }
    *(uint2*)(sm + OFF_CM + m2 * 8704 + i * 272 + r * 8) = me;
  }
  // x init from embedding (registers)
  float xr[16];
  {
    const float* er = emb + (size_t)z[(bid * 2 + m) * NA + ai] * DIM;
    float4 e0 = *(const float4*)&er[acg * 8];
    float4 e1 = *(const float4*)&er[acg * 8 + 4];
    float4 e2 = *(const float4*)&er[64 + acg * 8];
    float4 e3 = *(const float4*)&er[64 + acg * 8 + 4];
    xr[0] = e0.x; xr[1] = e0.y; xr[2]  = e0.z; xr[3]  = e0.w;
    xr[4] = e1.x; xr[5] = e1.y; xr[6]  = e1.z; xr[7]  = e1.w;
    xr[8] = e2.x; xr[9] = e2.y; xr[10] = e2.z; xr[11] = e2.w;
    xr[12] = e3.x; xr[13] = e3.y; xr[14] = e3.z; xr[15] = e3.w;
  }
  __syncthreads();                           // metadata complete; POS dead

  uint4 pt0, pt1, pt2, pt3, pt4, pt5;        // TAB prefetch (2924 uint4)

  // ================ 6 interaction layers ================
  for (int l = 0; l < NLAYER; ++l) {
    const short* wiL  = wiT  + (size_t)l * 16384;
    const short* wo1L = wo1T + (size_t)l * 16384;
    const short* wo2L = wo2T + (size_t)l * 16384;
    const short* tabL = tabA + (size_t)l * NTAB * 136;
    const float bo1r = bo1[l * DIM + wl * 32 + lr];
    const float bo2r = bo2[l * DIM + wl * 32 + lr];
    const int col = wl * 32 + lr;

    // ---- A: xr += VX (l>0) ; XB <- xr ; issue TAB (pt) ----
    if (l > 0) {
      uint4 v0 = *(const uint4*)(XFm + ai * 272 + cgo);
      uint4 v1 = *(const uint4*)(XFm + ai * 272 + cgo + 128);
      h2 hv;
      hv = __builtin_bit_cast(h2, v0.x); xr[0]  += (float)hv[0]; xr[1]  += (float)hv[1];
      hv = __builtin_bit_cast(h2, v0.y); xr[2]  += (float)hv[0]; xr[3]  += (float)hv[1];
      hv = __builtin_bit_cast(h2, v0.z); xr[4]  += (float)hv[0]; xr[5]  += (float)hv[1];
      hv = __builtin_bit_cast(h2, v0.w); xr[6]  += (float)hv[0]; xr[7]  += (float)hv[1];
      hv = __builtin_bit_cast(h2, v1.x); xr[8]  += (float)hv[0]; xr[9]  += (float)hv[1];
      hv = __builtin_bit_cast(h2, v1.y); xr[10] += (float)hv[0]; xr[11] += (float)hv[1];
      hv = __builtin_bit_cast(h2, v1.z); xr[12] += (float)hv[0]; xr[13] += (float)hv[1];
      hv = __builtin_bit_cast(h2, v1.w); xr[14] += (float)hv[0]; xr[15] += (float)hv[1];
    }
    {
      uint4 s0, s1;
      s0.x = pk2_f16(xr[0], xr[1]);   s0.y = pk2_f16(xr[2], xr[3]);
      s0.z = pk2_f16(xr[4], xr[5]);   s0.w = pk2_f16(xr[6], xr[7]);
      s1.x = pk2_f16(xr[8], xr[9]);   s1.y = pk2_f16(xr[10], xr[11]);
      s1.z = pk2_f16(xr[12], xr[13]); s1.w = pk2_f16(xr[14], xr[15]);
      *(uint4*)(XBm + ai * 272 + cgo) = s0;
      *(uint4*)(XBm + ai * 272 + cgo + 128) = s1;
    }
    {
      const uint4* s4 = (const uint4*)tabL;
      pt0 = s4[t]; pt1 = s4[t + 512]; pt2 = s4[t + 1024];
      pt3 = s4[t + 1536]; pt4 = s4[t + 2048];
      if (t < 364) pt5 = s4[t + 2560];
    }
    __syncthreads();

    // ---- P1: xf = x @ Wi (A from LDS, B from global) ; epilogue -> f16 XF ----
    {
      uint4 bf[8];
#pragma unroll
      for (int ks = 0; ks < 8; ++ks)
        bf[ks] = *(const uint4*)(wiL + (ks * 2 + hl) * 1024 + col * 8);
      f32x16 acc;
#pragma unroll
      for (int q = 0; q < 16; ++q) acc[q] = 0.0f;
#pragma unroll
      for (int ks = 0; ks < 8; ++ks) {
        hf8 a = ldsH(XBm + lr * 272 + ks * 32 + hl * 16);
        acc = __builtin_amdgcn_mfma_f32_32x32x16_f16(a, asH(bf[ks]), acc, 0, 0, 0);
      }
#pragma unroll
      for (int rg = 0; rg < 16; rg += 2) {
        int row = (rg & 3) + 8 * (rg >> 2) + 4 * hl;
        unsigned pk = pk2_f16(acc[rg], acc[rg + 1]);
        *(unsigned short*)(XFm + row * 272 + col * 2) = (unsigned short)pk;
        *(unsigned short*)(XFm + (row + 1) * 272 + col * 2) = (unsigned short)(pk >> 16);
      }
    }
    __syncthreads();

    // ---- B: ds_write TAB (pt) ----
    ((uint4*)(sm + OFF_TAB))[t] = pt0;
    ((uint4*)(sm + OFF_TAB))[t + 512] = pt1;
    ((uint4*)(sm + OFF_TAB))[t + 1024] = pt2;
    ((uint4*)(sm + OFF_TAB))[t + 1536] = pt3;
    ((uint4*)(sm + OFF_TAB))[t + 2048] = pt4;
    if (t < 364) ((uint4*)(sm + OFF_TAB))[t + 2560] = pt5;
    __syncthreads();

    // ---- P3: aggregation, 16x2 rounds; 1 b128 meta + 12 b128 data / pair ----
    h2 acc_h[8];
#pragma unroll
    for (int q = 0; q < 8; ++q) acc_h[q] = (h2)(_Float16)0.0f;
#pragma unroll 2
    for (int k = 0; k < 16; ++k) {
      uint4 ME = *(const uint4*)(CMm + ai * 272 + k * 16);   // rounds 2k, 2k+1
#define AGROUND(mex, mey)                                                 \
      {                                                                   \
        int foff = (int)((mex) & 0xFFFFu);                                \
        int gboff = (int)((mex) >> 16);                                   \
        unsigned a = (mey);                                               \
        h2 a00h = __builtin_bit_cast(h2, __builtin_amdgcn_perm(a, a, 0x01000100u)); \
        h2 a11h = __builtin_bit_cast(h2, __builtin_amdgcn_perm(a, a, 0x03020302u)); \
        const char* tp = sm + OFF_TAB + gboff + cgo;                      \
        uint4 T00 = *(const uint4*)(tp);                                  \
        uint4 T01 = *(const uint4*)(tp + 128);                            \
        uint4 T10 = *(const uint4*)(tp + 272);                            \
        uint4 T11 = *(const uint4*)(tp + 400);                            \
        const char* fp = XFm + foff + cgo;                                \
        uint4 F0 = *(const uint4*)(fp);                                   \
        uint4 F1 = *(const uint4*)(fp + 128);                             \
        h2 wv;                                                            \
        wv = a00h * __builtin_bit_cast(h2, T00.x) + a11h * __builtin_bit_cast(h2, T10.x); \
        acc_h[0] = wv * __builtin_bit_cast(h2, F0.x) + acc_h[0];          \
        wv = a00h * __builtin_bit_cast(h2, T00.y) + a11h * __builtin_bit_cast(h2, T10.y); \
        acc_h[1] = wv * __builtin_bit_cast(h2, F0.y) + acc_h[1];          \
        wv = a00h * __builtin_bit_cast(h2, T00.z) + a11h * __builtin_bit_cast(h2, T10.z); \
        acc_h[2] = wv * __builtin_bit_cast(h2, F0.z) + acc_h[2];          \
        wv = a00h * __builtin_bit_cast(h2, T00.w) + a11h * __builtin_bit_cast(h2, T10.w); \
        acc_h[3] = wv * __builtin_bit_cast(h2, F0.w) + acc_h[3];          \
        wv = a00h * __builtin_bit_cast(h2, T01.x) + a11h * __builtin_bit_cast(h2, T11.x); \
        acc_h[4] = wv * __builtin_bit_cast(h2, F1.x) + acc_h[4];          \
        wv = a00h * __builtin_bit_cast(h2, T01.y) + a11h * __builtin_bit_cast(h2, T11.y); \
        acc_h[5] = wv * __builtin_bit_cast(h2, F1.y) + acc_h[5];          \
        wv = a00h * __builtin_bit_cast(h2, T01.z) + a11h * __builtin_bit_cast(h2, T11.z); \
        acc_h[6] = wv * __builtin_bit_cast(h2, F1.z) + acc_h[6];          \
        wv = a00h * __builtin_bit_cast(h2, T01.w) + a11h * __builtin_bit_cast(h2, T11.w); \
        acc_h[7] = wv * __builtin_bit_cast(h2, F1.w) + acc_h[7];          \
      }
      AGROUND(ME.x, ME.y)
      AGROUND(ME.z, ME.w)
#undef AGROUND
    }
    __syncthreads();                     // TAB/XF reads done

    // ---- C: AGG <- acc_h (packed f16 direct store; overwrites dead XB) ----
    {
      uint4 s0, s1;
      s0.x = __builtin_bit_cast(unsigned, acc_h[0]);
      s0.y = __builtin_bit_cast(unsigned, acc_h[1]);
      s0.z = __builtin_bit_cast(unsigned, acc_h[2]);
      s0.w = __builtin_bit_cast(unsigned, acc_h[3]);
      s1.x = __builtin_bit_cast(unsigned, acc_h[4]);
      s1.y = __builtin_bit_cast(unsigned, acc_h[5]);
      s1.z = __builtin_bit_cast(unsigned, acc_h[6]);
      s1.w = __builtin_bit_cast(unsigned, acc_h[7]);
      *(uint4*)(AGm + ai * 272 + cgo) = s0;
      *(uint4*)(AGm + ai * 272 + cgo + 128) = s1;
    }
    __syncthreads();

    // ---- P5: t1 = ssp(agg @ Wo1 + bo1) (B from global) ----
    float t1v[16];
    {
      uint4 bf[8];
#pragma unroll
      for (int ks = 0; ks < 8; ++ks)
        bf[ks] = *(const uint4*)(wo1L + (ks * 2 + hl) * 1024 + col * 8);
      f32x16 acc;
#pragma unroll
      for (int q = 0; q < 16; ++q) acc[q] = 0.0f;
#pragma unroll
      for (int ks = 0; ks < 8; ++ks) {
        hf8 a = ldsH(AGm + lr * 272 + ks * 32 + hl * 16);
        acc = __builtin_amdgcn_mfma_f32_32x32x16_f16(a, asH(bf[ks]), acc, 0, 0, 0);
      }
#pragma unroll
      for (int rg = 0; rg < 16; ++rg) t1v[rg] = ssp_f(acc[rg] + bo1r);
    }
    __syncthreads();

    // ---- D: t1 -> AGm ----
    {
#pragma unroll
      for (int rg = 0; rg < 16; rg += 2) {
        int row = (rg & 3) + 8 * (rg >> 2) + 4 * hl;
        unsigned pk = pk2_f16(t1v[rg], t1v[rg + 1]);
        *(unsigned short*)(AGm + row * 272 + col * 2) = (unsigned short)pk;
        *(unsigned short*)(AGm + (row + 1) * 272 + col * 2) = (unsigned short)(pk >> 16);
      }
    }
    __syncthreads();

    // ---- P7: v = t1 @ Wo2 + bo2 -> VX f16 (XF region) ----
    {
      uint4 bf[8];
#pragma unroll
      for (int ks = 0; ks < 8; ++ks)
        bf[ks] = *(const uint4*)(wo2L + (ks * 2 + hl) * 1024 + col * 8);
      f32x16 acc;
#pragma unroll
      for (int q = 0; q < 16; ++q) acc[q] = 0.0f;
#pragma unroll
      for (int ks = 0; ks < 8; ++ks) {
        hf8 a = ldsH(AGm + lr * 272 + ks * 32 + hl * 16);
        acc = __builtin_amdgcn_mfma_f32_32x32x16_f16(a, asH(bf[ks]), acc, 0, 0, 0);
      }
#pragma unroll
      for (int rg = 0; rg < 16; rg += 2) {
        int row = (rg & 3) + 8 * (rg >> 2) + 4 * hl;
        unsigned pk = pk2_f16(acc[rg] + bo2r, acc[rg + 1] + bo2r);
        *(unsigned short*)(XFm + row * 272 + col * 2) = (unsigned short)pk;
        *(unsigned short*)(XFm + (row + 1) * 272 + col * 2) = (unsigned short)(pk >> 16);
      }
    }
    __syncthreads();
  }

  // ---- final residual: xr += VX (last layer) ----
  {
    uint4 v0 = *(const uint4*)(XFm + ai * 272 + cgo);
    uint4 v1 = *(const uint4*)(XFm + ai * 272 + cgo + 128);
    h2 hv;
    hv = __builtin_bit_cast(h2, v0.x); xr[0]  += (float)hv[0]; xr[1]  += (float)hv[1];
    hv = __builtin_bit_cast(h2, v0.y); xr[2]  += (float)hv[0]; xr[3]  += (float)hv[1];
    hv = __builtin_bit_cast(h2, v0.z); xr[4]  += (float)hv[0]; xr[5]  += (float)hv[1];
    hv = __builtin_bit_cast(h2, v0.w); xr[6]  += (float)hv[0]; xr[7]  += (float)hv[1];
    hv = __builtin_bit_cast(h2, v1.x); xr[8]  += (float)hv[0]; xr[9]  += (float)hv[1];
    hv = __builtin_bit_cast(h2, v1.y); xr[10] += (float)hv[0]; xr[11] += (float)hv[1];
    hv = __builtin_bit_cast(h2, v1.z); xr[12] += (float)hv[0]; xr[13] += (float)hv[1];
    hv = __builtin_bit_cast(h2, v1.w); xr[14] += (float)hv[0]; xr[15] += (float)hv[1];
  }

  // ================ pooling + head ================
#pragma unroll
  for (int off = 1; off < 32; off <<= 1) {
#pragma unroll
    for (int q = 0; q < 16; ++q) xr[q] += __shfl_xor(xr[q], off);
  }
  float* molS = (float*)(sm + 0);        // [2][132]
  float* hsum = (float*)(sm + 2048);     // [2][128]
  if (ai == 0) {
#pragma unroll
    for (int q = 0; q < 8; ++q) molS[m * 132 + acg * 8 + q] = xr[q];
#pragma unroll
    for (int q = 0; q < 8; ++q) molS[m * 132 + 64 + acg * 8 + q] = xr[8 + q];
  }
  __syncthreads();
  if (t < 256) {
    int mm = t >> 7, c = t & 127;
    float h = bh1[c];
#pragma unroll 8
    for (int k = 0; k < 128; ++k) h += molS[mm * 132 + k] * Wh1[k * 128 + c];
    h = h / (1.0f + __expf(-h));         // silu
    hsum[mm * 128 + c] = h * Wh2[c];
  }
  for (int off = 64; off > 0; off >>= 1) {
    __syncthreads();
    if (t < 256) {
      int mm = t >> 7, c = t & 127;
      if (c < off) hsum[mm * 128 + c] += hsum[mm * 128 + c + off];
    }
  }
  __syncthreads();
  if (t < 2) out[bid * 2 + t] = hsum[t * 128] + bh2[0];
}

// ------------------------------------------------------------ launcher
extern "C" void kernel_launch(void* const* d_in, const int* in_sizes, int n_in,
                              void* d_out, int out_size, void* d_ws, size_t ws_size,
                              hipStream_t stream) {
  const int*   z    = (const int*)d_in[0];
  const float* pos  = (const float*)d_in[1];
  const float* emb  = (const float*)d_in[6];
  const float* Wi   = (const float*)d_in[7];
  const float* Wf1  = (const float*)d_in[8];
  const float* bf1  = (const float*)d_in[9];
  const float* Wf2  = (const float*)d_in[10];
  const float* bf2  = (const float*)d_in[11];
  const float* Wo1  = (const float*)d_in[12];
  const float* bo1  = (const float*)d_in[13];
  const float* Wo2  = (const float*)d_in[14];
  const float* bo2  = (const float*)d_in[15];
  const float* Wh1  = (const float*)d_in[16];
  const float* bh1  = (const float*)d_in[17];
  const float* Wh2  = (const float*)d_in[18];
  const float* bh2  = (const float*)d_in[19];
  float* out = (float*)d_out;

  short* wsS = (short*)d_ws;
  const short* wiT  = wsS + WS_WIT  / 2;
  const short* wo1T = wsS + WS_WO1T / 2;
  const short* wo2T = wsS + WS_WO2T / 2;
  const short* tab  = wsS + WS_TAB  / 2;

  (void)hipFuncSetAttribute(reinterpret_cast<const void*>(k_fused),
                            hipFuncAttributeMaxDynamicSharedMemorySize, LDS_TOTAL);

  k_prep<<<dim3(64, 3, 6), 256, 0, stream>>>(Wi, Wo1, Wo2, wsS);
  k_tab<<<dim3(NTAB, 6), 128, 0, stream>>>(Wf1, bf1, Wf2, bf2, wsS + WS_TAB / 2);
  k_fused<<<NMOL / 2, 512, LDS_TOTAL, stream>>>(
      z, pos, emb, wiT, wo1T, wo2T, tab, bo1, bo2, Wh1, bh1, Wh2, bh2, out);
}

// Round 21
// 109.771 us; speedup vs baseline: 1.8535x; 1.0790x over previous
//
#include <hip/hip_runtime.h>
#include <math.h>

// Problem constants (fixed by setup_inputs)
#define TOTAL  32768   // B * N_PER_MOL
#define NMOL   1024
#define NA     32
#define DIM    128
#define NRBF   50
#define NLAYER 6

typedef __attribute__((ext_vector_type(16))) float f32x16;
typedef _Float16 h2 __attribute__((ext_vector_type(2)));
typedef __fp16 hf8 __attribute__((ext_vector_type(8)));   // MFMA operand container

// ------------------------------------------------------------ LDS layout (bytes)
// Rows: 272 B (136 f16) -> 4-bank rotate per row.
// TAB region [0, 46784) (NTAB=172); aliases:
//   XB (phase A->P1) and AGG/t1 (C->P7) share [29376,46784) -- disjoint lives.
// XF [46784,64192): xf (P1->P3) then VX (P7->next A); POS aliases in setup.
// CM [64192,81600): compacted alive-pair meta [m][atom]: row = atom*272 B,
//   32 u64 slots {(gboff<<16)|foff, pk_f16(a0,a1)}, zero-padded past the
//   atom's alive count; per-molecule even max count at row0 + 256.
#define OFF_TAB  0
#define OFF_XBAG 29376
#define OFF_XF   46784
#define OFF_POS  46784     // setup-only alias
#define OFF_CM   64192
#define LDS_TOTAL 81600    // 2 blocks/CU (2x81600 <= 163840)

// ------------------------------------------------------------ ws layout (bytes)
// Weights repacked for coalesced direct-from-global MFMA B-fragments:
//   wX[l][(k>>3)][col][k&7] f16, 128x128 per layer = 32768 B
#define WS_WIT   0          // 6 * 32768 = 196608
#define WS_WO1T  196608
#define WS_WO2T  393216
#define WS_TAB   655360     // 6 * 172*136*2 = 280704

#define KSTEP  0.10204081632653061f   /* 5/49 */
#define C1     -48.0200005f           /* -0.5*(49/5)^2 */
#define NTAB   172
#define TSCALE 34.2f                  /* 171/5 */

// ------------------------------------------------------------ helpers
__device__ __forceinline__ unsigned pk2_f16(float lo, float hi) {  // v_cvt_pkrtz_f16_f32
  return __builtin_bit_cast(unsigned, __builtin_amdgcn_cvt_pkrtz(lo, hi));
}
__device__ __forceinline__ float ssp_f(float v) {    // softplus(v) - ln2
  float e = __expf(-fabsf(v));
  return fmaxf(v, 0.0f) + __logf(1.0f + e) - 0.69314718055994531f;
}
__device__ __forceinline__ hf8 ldsH(const char* p) {      // one ds_read_b128
  return __builtin_bit_cast(hf8, *reinterpret_cast<const uint4*>(p));
}
__device__ __forceinline__ hf8 asH(uint4 u) {
  return __builtin_bit_cast(hf8, u);
}
// round-robin inverse map: (round r, atom i) -> partner j
__device__ __forceinline__ int inv_partner(int r, int i) {
  if (i == 31) return r;
  int mm = i - r; if (mm < 0) mm += 31;
  if (mm == 0) return 31;
  int jj = 2 * r - i; jj %= 31; if (jj < 0) jj += 31;
  return jj;
}

// ------------------------------------------------------------ weight prep (cold, f16)
__global__ void k_prep(const float* __restrict__ Wi, const float* __restrict__ Wo1,
                       const float* __restrict__ Wo2, short* __restrict__ ws) {
  const int kind = blockIdx.y, l = blockIdx.z;
  const int idx = blockIdx.x * 256 + threadIdx.x;   // 64*256 = 16384 = 128*128
  int k = idx >> 7, c = idx & 127;
  const float* s = (kind == 0) ? Wi : (kind == 1) ? Wo1 : Wo2;
  size_t base = (kind == 0) ? WS_WIT : (kind == 1) ? WS_WO1T : WS_WO2T;
  float v = s[(size_t)l * DIM * DIM + k * DIM + c];
  ws[base / 2 + (size_t)l * 16384 + (k >> 3) * 1024 + c * 8 + (k & 7)] =
      (short)__builtin_bit_cast(unsigned short, (_Float16)v);
}

// ------------------------------------------------------------ filter table (cold, f16)
__global__ void k_tab(const float* __restrict__ Wf1, const float* __restrict__ bf1,
                      const float* __restrict__ Wf2, const float* __restrict__ bf2,
                      short* __restrict__ tab) {
  __shared__ float fs[64];
  __shared__ float hs[128];
  const int g = blockIdx.x, l = blockIdx.y, c = threadIdx.x;
  const float d = (float)g * (5.0f / 171.0f);
  if (c < NRBF) { float tt = d - (float)c * KSTEP; fs[c] = __expf(C1 * tt * tt); }
  __syncthreads();
  float h = bf1[l * DIM + c];
#pragma unroll 5
  for (int k = 0; k < NRBF; ++k) h += fs[k] * Wf1[((size_t)l * NRBF + k) * DIM + c];
  hs[c] = ssp_f(h);
  __syncthreads();
  float wv = bf2[l * DIM + c];
#pragma unroll 8
  for (int k = 0; k < DIM; ++k) wv += hs[k] * Wf2[((size_t)l * DIM + k) * DIM + c];
  tab[((size_t)l * NTAB + g) * 136 + c] =
      (short)__builtin_bit_cast(unsigned short, (_Float16)wv);
}

// ------------------------------------------------------------ fully fused network
// 2 molecules per block; x resident in registers (16 f32/thread) through all
// 6 layers + pooling + head. Waves 0-3 -> mol A, 4-7 -> mol B. 2 blocks/CU.
// MFMA B-operands straight from global (coalesced, L1/L2-resident); interp
// table LDS-staged async; P3 iterates only alive (d < cutoff) pairs,
// compacted per atom, bound = per-molecule max (wave-uniform, branchless).
__global__ __launch_bounds__(512, 4) void k_fused(
    const int* __restrict__ z, const float* __restrict__ pos,
    const float* __restrict__ emb,
    const short* __restrict__ wiT, const short* __restrict__ wo1T,
    const short* __restrict__ wo2T, const short* __restrict__ tabA,
    const float* __restrict__ bo1, const float* __restrict__ bo2,
    const float* __restrict__ Wh1, const float* __restrict__ bh1,
    const float* __restrict__ Wh2, const float* __restrict__ bh2,
    float* __restrict__ out) {
  extern __shared__ char sm[];
  const int t = threadIdx.x;
  const int bid = blockIdx.x;
  const int w = t >> 6, lane = t & 63, hl = lane >> 5, lr = lane & 31;
  const int m = w >> 2, wl = w & 3;        // m == t>>8
  const int ai = t & 31;                   // owned atom
  const int acg = (t >> 5) & 7;            // channel group
  const int cgo = acg * 16;                // byte offset (8 ch)

  char*  XBm = sm + OFF_XBAG + m * 8704;   // XB and AGG/t1 (disjoint live ranges)
  char*  AGm = XBm;
  char*  XFm = sm + OFF_XF + m * 8704;
  float* poss = (float*)(sm + OFF_POS);    // setup-only alias
  const char* CMm = sm + OFF_CM + m * 8704;

  // ================ setup (once) ================
  if (t < 192) poss[t] = pos[(size_t)bid * 192 + t];
  __syncthreads();
  // compact alive pairs per (mol, atom): thread t<64 -> (m2 = t>>5, i = t&31)
  if (t < 64) {
    const int m2 = t >> 5, i = t & 31;
    const float* pm = poss + m2 * 96;
    const float xi = pm[i * 3 + 0], yi = pm[i * 3 + 1], zi = pm[i * 3 + 2];
    char* row = sm + OFF_CM + m2 * 8704 + i * 272;
    int n = 0;
    for (int r = 0; r < 31; ++r) {
      int j = inv_partner(r, i);
      float dx = pm[j * 3 + 0] - xi;
      float dy = pm[j * 3 + 1] - yi;
      float dz = pm[j * 3 + 2] - zi;
      float d = sqrtf(dx * dx + dy * dy + dz * dz);
      if (d < 5.0f) {
        float rc = 0.5f * (__cosf(d * 0.62831853071795865f) + 1.0f);
        float u0 = fminf(d * TSCALE, 170.0f);
        int g = (int)u0;
        float f = u0 - (float)g;
        uint2 me;
        me.x = ((unsigned)(g * 272) << 16) | (unsigned)(j * 272);
        me.y = pk2_f16((1.0f - f) * rc, f * rc);
        *(uint2*)(row + n * 8) = me;
        ++n;
      }
    }
    for (int s = n; s < 32; ++s) { uint2 zz; zz.x = 0u; zz.y = 0u; *(uint2*)(row + s * 8) = zz; }
    // per-molecule max alive count (even-rounded), lanes 0-31 / 32-63 reduce
    int mx = n;
#pragma unroll
    for (int off = 1; off < 32; off <<= 1) mx = max(mx, __shfl_xor(mx, off));
    if ((t & 31) == 0) *(int*)(sm + OFF_CM + m2 * 8704 + 256) = (mx + 1) & ~1;
  }
  // x init from embedding (registers)
  float xr[16];
  {
    const float* er = emb + (size_t)z[(bid * 2 + m) * NA + ai] * DIM;
    float4 e0 = *(const float4*)&er[acg * 8];
    float4 e1 = *(const float4*)&er[acg * 8 + 4];
    float4 e2 = *(const float4*)&er[64 + acg * 8];
    float4 e3 = *(const float4*)&er[64 + acg * 8 + 4];
    xr[0] = e0.x; xr[1] = e0.y; xr[2]  = e0.z; xr[3]  = e0.w;
    xr[4] = e1.x; xr[5] = e1.y; xr[6]  = e1.z; xr[7]  = e1.w;
    xr[8] = e2.x; xr[9] = e2.y; xr[10] = e2.z; xr[11] = e2.w;
    xr[12] = e3.x; xr[13] = e3.y; xr[14] = e3.z; xr[15] = e3.w;
  }
  __syncthreads();                           // metadata complete; POS dead

  const int nmax = *(const int*)(CMm + 256); // wave-uniform, even, <= 32

  uint4 pt0, pt1, pt2, pt3, pt4, pt5;        // TAB prefetch (2924 uint4)

  // ================ 6 interaction layers ================
  for (int l = 0; l < NLAYER; ++l) {
    const short* wiL  = wiT  + (size_t)l * 16384;
    const short* wo1L = wo1T + (size_t)l * 16384;
    const short* wo2L = wo2T + (size_t)l * 16384;
    const short* tabL = tabA + (size_t)l * NTAB * 136;
    const float bo1r = bo1[l * DIM + wl * 32 + lr];
    const float bo2r = bo2[l * DIM + wl * 32 + lr];
    const int col = wl * 32 + lr;

    // ---- A: xr += VX (l>0) ; XB <- xr ; issue TAB (pt) ----
    if (l > 0) {
      uint4 v0 = *(const uint4*)(XFm + ai * 272 + cgo);
      uint4 v1 = *(const uint4*)(XFm + ai * 272 + cgo + 128);
      h2 hv;
      hv = __builtin_bit_cast(h2, v0.x); xr[0]  += (float)hv[0]; xr[1]  += (float)hv[1];
      hv = __builtin_bit_cast(h2, v0.y); xr[2]  += (float)hv[0]; xr[3]  += (float)hv[1];
      hv = __builtin_bit_cast(h2, v0.z); xr[4]  += (float)hv[0]; xr[5]  += (float)hv[1];
      hv = __builtin_bit_cast(h2, v0.w); xr[6]  += (float)hv[0]; xr[7]  += (float)hv[1];
      hv = __builtin_bit_cast(h2, v1.x); xr[8]  += (float)hv[0]; xr[9]  += (float)hv[1];
      hv = __builtin_bit_cast(h2, v1.y); xr[10] += (float)hv[0]; xr[11] += (float)hv[1];
      hv = __builtin_bit_cast(h2, v1.z); xr[12] += (float)hv[0]; xr[13] += (float)hv[1];
      hv = __builtin_bit_cast(h2, v1.w); xr[14] += (float)hv[0]; xr[15] += (float)hv[1];
    }
    {
      uint4 s0, s1;
      s0.x = pk2_f16(xr[0], xr[1]);   s0.y = pk2_f16(xr[2], xr[3]);
      s0.z = pk2_f16(xr[4], xr[5]);   s0.w = pk2_f16(xr[6], xr[7]);
      s1.x = pk2_f16(xr[8], xr[9]);   s1.y = pk2_f16(xr[10], xr[11]);
      s1.z = pk2_f16(xr[12], xr[13]); s1.w = pk2_f16(xr[14], xr[15]);
      *(uint4*)(XBm + ai * 272 + cgo) = s0;
      *(uint4*)(XBm + ai * 272 + cgo + 128) = s1;
    }
    {
      const uint4* s4 = (const uint4*)tabL;
      pt0 = s4[t]; pt1 = s4[t + 512]; pt2 = s4[t + 1024];
      pt3 = s4[t + 1536]; pt4 = s4[t + 2048];
      if (t < 364) pt5 = s4[t + 2560];
    }
    __syncthreads();

    // ---- P1: xf = x @ Wi (A from LDS, B from global) ; epilogue -> f16 XF ----
    {
      uint4 bf[8];
#pragma unroll
      for (int ks = 0; ks < 8; ++ks)
        bf[ks] = *(const uint4*)(wiL + (ks * 2 + hl) * 1024 + col * 8);
      f32x16 acc;
#pragma unroll
      for (int q = 0; q < 16; ++q) acc[q] = 0.0f;
#pragma unroll
      for (int ks = 0; ks < 8; ++ks) {
        hf8 a = ldsH(XBm + lr * 272 + ks * 32 + hl * 16);
        acc = __builtin_amdgcn_mfma_f32_32x32x16_f16(a, asH(bf[ks]), acc, 0, 0, 0);
      }
#pragma unroll
      for (int rg = 0; rg < 16; rg += 2) {
        int row = (rg & 3) + 8 * (rg >> 2) + 4 * hl;
        unsigned pk = pk2_f16(acc[rg], acc[rg + 1]);
        *(unsigned short*)(XFm + row * 272 + col * 2) = (unsigned short)pk;
        *(unsigned short*)(XFm + (row + 1) * 272 + col * 2) = (unsigned short)(pk >> 16);
      }
    }
    __syncthreads();

    // ---- B: ds_write TAB (pt) ----
    ((uint4*)(sm + OFF_TAB))[t] = pt0;
    ((uint4*)(sm + OFF_TAB))[t + 512] = pt1;
    ((uint4*)(sm + OFF_TAB))[t + 1024] = pt2;
    ((uint4*)(sm + OFF_TAB))[t + 1536] = pt3;
    ((uint4*)(sm + OFF_TAB))[t + 2048] = pt4;
    if (t < 364) ((uint4*)(sm + OFF_TAB))[t + 2560] = pt5;
    __syncthreads();

    // ---- P3: aggregation over alive pairs only (nmax wave-uniform) ----
    h2 acc_h[8];
#pragma unroll
    for (int q = 0; q < 8; ++q) acc_h[q] = (h2)(_Float16)0.0f;
    for (int k = 0; k < nmax; k += 2) {
      uint4 ME = *(const uint4*)(CMm + ai * 272 + k * 8);   // slots k, k+1
#define AGROUND(mex, mey)                                                 \
      {                                                                   \
        int foff = (int)((mex) & 0xFFFFu);                                \
        int gboff = (int)((mex) >> 16);                                   \
        unsigned a = (mey);                                               \
        h2 a00h = __builtin_bit_cast(h2, __builtin_amdgcn_perm(a, a, 0x01000100u)); \
        h2 a11h = __builtin_bit_cast(h2, __builtin_amdgcn_perm(a, a, 0x03020302u)); \
        const char* tp = sm + OFF_TAB + gboff + cgo;                      \
        uint4 T00 = *(const uint4*)(tp);                                  \
        uint4 T01 = *(const uint4*)(tp + 128);                            \
        uint4 T10 = *(const uint4*)(tp + 272);                            \
        uint4 T11 = *(const uint4*)(tp + 400);                            \
        const char* fp = XFm + foff + cgo;                                \
        uint4 F0 = *(const uint4*)(fp);                                   \
        uint4 F1 = *(const uint4*)(fp + 128);                             \
        h2 wv;                                                            \
        wv = a00h * __builtin_bit_cast(h2, T00.x) + a11h * __builtin_bit_cast(h2, T10.x); \
        acc_h[0] = wv * __builtin_bit_cast(h2, F0.x) + acc_h[0];          \
        wv = a00h * __builtin_bit_cast(h2, T00.y) + a11h * __builtin_bit_cast(h2, T10.y); \
        acc_h[1] = wv * __builtin_bit_cast(h2, F0.y) + acc_h[1];          \
        wv = a00h * __builtin_bit_cast(h2, T00.z) + a11h * __builtin_bit_cast(h2, T10.z); \
        acc_h[2] = wv * __builtin_bit_cast(h2, F0.z) + acc_h[2];          \
        wv = a00h * __builtin_bit_cast(h2, T00.w) + a11h * __builtin_bit_cast(h2, T10.w); \
        acc_h[3] = wv * __builtin_bit_cast(h2, F0.w) + acc_h[3];          \
        wv = a00h * __builtin_bit_cast(h2, T01.x) + a11h * __builtin_bit_cast(h2, T11.x); \
        acc_h[4] = wv * __builtin_bit_cast(h2, F1.x) + acc_h[4];          \
        wv = a00h * __builtin_bit_cast(h2, T01.y) + a11h * __builtin_bit_cast(h2, T11.y); \
        acc_h[5] = wv * __builtin_bit_cast(h2, F1.y) + acc_h[5];          \
        wv = a00h * __builtin_bit_cast(h2, T01.z) + a11h * __builtin_bit_cast(h2, T11.z); \
        acc_h[6] = wv * __builtin_bit_cast(h2, F1.z) + acc_h[6];          \
        wv = a00h * __builtin_bit_cast(h2, T01.w) + a11h * __builtin_bit_cast(h2, T11.w); \
        acc_h[7] = wv * __builtin_bit_cast(h2, F1.w) + acc_h[7];          \
      }
      AGROUND(ME.x, ME.y)
      AGROUND(ME.z, ME.w)
#undef AGROUND
    }
    __syncthreads();                     // TAB/XF reads done

    // ---- C: AGG <- acc_h (packed f16 direct store; overwrites dead XB) ----
    {
      uint4 s0, s1;
      s0.x = __builtin_bit_cast(unsigned, acc_h[0]);
      s0.y = __builtin_bit_cast(unsigned, acc_h[1]);
      s0.z = __builtin_bit_cast(unsigned, acc_h[2]);
      s0.w = __builtin_bit_cast(unsigned, acc_h[3]);
      s1.x = __builtin_bit_cast(unsigned, acc_h[4]);
      s1.y = __builtin_bit_cast(unsigned, acc_h[5]);
      s1.z = __builtin_bit_cast(unsigned, acc_h[6]);
      s1.w = __builtin_bit_cast(unsigned, acc_h[7]);
      *(uint4*)(AGm + ai * 272 + cgo) = s0;
      *(uint4*)(AGm + ai * 272 + cgo + 128) = s1;
    }
    __syncthreads();

    // ---- P5: t1 = ssp(agg @ Wo1 + bo1) (B from global) ----
    float t1v[16];
    {
      uint4 bf[8];
#pragma unroll
      for (int ks = 0; ks < 8; ++ks)
        bf[ks] = *(const uint4*)(wo1L + (ks * 2 + hl) * 1024 + col * 8);
      f32x16 acc;
#pragma unroll
      for (int q = 0; q < 16; ++q) acc[q] = 0.0f;
#pragma unroll
      for (int ks = 0; ks < 8; ++ks) {
        hf8 a = ldsH(AGm + lr * 272 + ks * 32 + hl * 16);
        acc = __builtin_amdgcn_mfma_f32_32x32x16_f16(a, asH(bf[ks]), acc, 0, 0, 0);
      }
#pragma unroll
      for (int rg = 0; rg < 16; ++rg) t1v[rg] = ssp_f(acc[rg] + bo1r);
    }
    __syncthreads();

    // ---- D: t1 -> AGm ----
    {
#pragma unroll
      for (int rg = 0; rg < 16; rg += 2) {
        int row = (rg & 3) + 8 * (rg >> 2) + 4 * hl;
        unsigned pk = pk2_f16(t1v[rg], t1v[rg + 1]);
        *(unsigned short*)(AGm + row * 272 + col * 2) = (unsigned short)pk;
        *(unsigned short*)(AGm + (row + 1) * 272 + col * 2) = (unsigned short)(pk >> 16);
      }
    }
    __syncthreads();

    // ---- P7: v = t1 @ Wo2 + bo2 -> VX f16 (XF region) ----
    {
      uint4 bf[8];
#pragma unroll
      for (int ks = 0; ks < 8; ++ks)
        bf[ks] = *(const uint4*)(wo2L + (ks * 2 + hl) * 1024 + col * 8);
      f32x16 acc;
#pragma unroll
      for (int q = 0; q < 16; ++q) acc[q] = 0.0f;
#pragma unroll
      for (int ks = 0; ks < 8; ++ks) {
        hf8 a = ldsH(AGm + lr * 272 + ks * 32 + hl * 16);
        acc = __builtin_amdgcn_mfma_f32_32x32x16_f16(a, asH(bf[ks]), acc, 0, 0, 0);
      }
#pragma unroll
      for (int rg = 0; rg < 16; rg += 2) {
        int row = (rg & 3) + 8 * (rg >> 2) + 4 * hl;
        unsigned pk = pk2_f16(acc[rg] + bo2r, acc[rg + 1] + bo2r);
        *(unsigned short*)(XFm + row * 272 + col * 2) = (unsigned short)pk;
        *(unsigned short*)(XFm + (row + 1) * 272 + col * 2) = (unsigned short)(pk >> 16);
      }
    }
    __syncthreads();
  }

  // ---- final residual: xr += VX (last layer) ----
  {
    uint4 v0 = *(const uint4*)(XFm + ai * 272 + cgo);
    uint4 v1 = *(const uint4*)(XFm + ai * 272 + cgo + 128);
    h2 hv;
    hv = __builtin_bit_cast(h2, v0.x); xr[0]  += (float)hv[0]; xr[1]  += (float)hv[1];
    hv = __builtin_bit_cast(h2, v0.y); xr[2]  += (float)hv[0]; xr[3]  += (float)hv[1];
    hv = __builtin_bit_cast(h2, v0.z); xr[4]  += (float)hv[0]; xr[5]  += (float)hv[1];
    hv = __builtin_bit_cast(h2, v0.w); xr[6]  += (float)hv[0]; xr[7]  += (float)hv[1];
    hv = __builtin_bit_cast(h2, v1.x); xr[8]  += (float)hv[0]; xr[9]  += (float)hv[1];
    hv = __builtin_bit_cast(h2, v1.y); xr[10] += (float)hv[0]; xr[11] += (float)hv[1];
    hv = __builtin_bit_cast(h2, v1.z); xr[12] += (float)hv[0]; xr[13] += (float)hv[1];
    hv = __builtin_bit_cast(h2, v1.w); xr[14] += (float)hv[0]; xr[15] += (float)hv[1];
  }

  // ================ pooling + head ================
#pragma unroll
  for (int off = 1; off < 32; off <<= 1) {
#pragma unroll
    for (int q = 0; q < 16; ++q) xr[q] += __shfl_xor(xr[q], off);
  }
  float* molS = (float*)(sm + 0);        // [2][132]
  float* hsum = (float*)(sm + 2048);     // [2][128]
  if (ai == 0) {
#pragma unroll
    for (int q = 0; q < 8; ++q) molS[m * 132 + acg * 8 + q] = xr[q];
#pragma unroll
    for (int q = 0; q < 8; ++q) molS[m * 132 + 64 + acg * 8 + q] = xr[8 + q];
  }
  __syncthreads();
  if (t < 256) {
    int mm = t >> 7, c = t & 127;
    float h = bh1[c];
#pragma unroll 8
    for (int k = 0; k < 128; ++k) h += molS[mm * 132 + k] * Wh1[k * 128 + c];
    h = h / (1.0f + __expf(-h));         // silu
    hsum[mm * 128 + c] = h * Wh2[c];
  }
  for (int off = 64; off > 0; off >>= 1) {
    __syncthreads();
    if (t < 256) {
      int mm = t >> 7, c = t & 127;
      if (c < off) hsum[mm * 128 + c] += hsum[mm * 128 + c + off];
    }
  }
  __syncthreads();
  if (t < 2) out[bid * 2 + t] = hsum[t * 128] + bh2[0];
}

// ------------------------------------------------------------ launcher
extern "C" void kernel_launch(void* const* d_in, const int* in_sizes, int n_in,
                              void* d_out, int out_size, void* d_ws, size_t ws_size,
                              hipStream_t stream) {
  const int*   z    = (const int*)d_in[0];
  const float* pos  = (const float*)d_in[1];
  const float* emb  = (const float*)d_in[6];
  const float* Wi   = (const float*)d_in[7];
  const float* Wf1  = (const float*)d_in[8];
  const float* bf1  = (const float*)d_in[9];
  const float* Wf2  = (const float*)d_in[10];
  const float* bf2  = (const float*)d_in[11];
  const float* Wo1  = (const float*)d_in[12];
  const float* bo1  = (const float*)d_in[13];
  const float* Wo2  = (const float*)d_in[14];
  const float* bo2  = (const float*)d_in[15];
  const float* Wh1  = (const float*)d_in[16];
  const float* bh1  = (const float*)d_in[17];
  const float* Wh2  = (const float*)d_in[18];
  const float* bh2  = (const float*)d_in[19];
  float* out = (float*)d_out;

  short* wsS = (short*)d_ws;
  const short* wiT  = wsS + WS_WIT  / 2;
  const short* wo1T = wsS + WS_WO1T / 2;
  const short* wo2T = wsS + WS_WO2T / 2;
  const short* tab  = wsS + WS_TAB  / 2;

  (void)hipFuncSetAttribute(reinterpret_cast<const void*>(k_fused),
                            hipFuncAttributeMaxDynamicSharedMemorySize, LDS_TOTAL);

  k_prep<<<dim3(64, 3, 6), 256, 0, stream>>>(Wi, Wo1, Wo2, wsS);
  k_tab<<<dim3(NTAB, 6), 128, 0, stream>>>(Wf1, bf1, Wf2, bf2, wsS + WS_TAB / 2);
  k_fused<<<NMOL / 2, 512, LDS_TOTAL, stream>>>(
      z, pos, emb, wiT, wo1T, wo2T, tab, bo1, bo2, Wh1, bh1, Wh2, bh2, out);
}